// Round 1
// 603.449 us; speedup vs baseline: 1.0560x; 1.0560x over previous
//
#include <hip/hip_runtime.h>
#include <hip/hip_bf16.h>
#include <math.h>

#define N_NODES 50000
#define N_EDGES 800000
#define IN_SIZE 256
#define OUT_SIZE 128
#define EDGE_DIM 64
#define NCAT 576   // [q:0-127 | k:128-255 | v:256-383 | sk:384-511 | q2:512-575]

#define SCAN_B 256
#define NBLK ((N_NODES + SCAN_B - 1) / SCAN_B)   // 196

typedef __attribute__((ext_vector_type(8))) short short8;
typedef __attribute__((ext_vector_type(4))) float floatx4;

#define GPTR(p) ((const __attribute__((address_space(1))) void*)(p))
#define LPTR(p) ((__attribute__((address_space(3))) void*)(p))

__device__ __forceinline__ unsigned short f2bf(float f) {
    unsigned int u = __float_as_uint(f);
    unsigned int r = (u + 0x7fffu + ((u >> 16) & 1u)) >> 16;  // RNE
    return (unsigned short)r;
}
__device__ __forceinline__ float2 bf2_to_f2(unsigned int u) {
    float2 r;
    r.x = __uint_as_float(u << 16);
    r.y = __uint_as_float(u & 0xffff0000u);
    return r;
}
__device__ __forceinline__ void unp8(uint4 u, float* f) {
    float2 t;
    t = bf2_to_f2(u.x); f[0] = t.x; f[1] = t.y;
    t = bf2_to_f2(u.y); f[2] = t.x; f[3] = t.y;
    t = bf2_to_f2(u.z); f[4] = t.x; f[5] = t.y;
    t = bf2_to_f2(u.w); f[6] = t.x; f[7] = t.y;
}

// ---------------- x -> bf16 ----------------
__global__ __launch_bounds__(256) void xcast_kernel(
    const float* __restrict__ x, unsigned short* __restrict__ xb)
{
    size_t i = ((size_t)blockIdx.x * 256 + threadIdx.x) * 4;
    float4 v = *(const float4*)(x + i);
    uint2 p;
    p.x = (unsigned int)f2bf(v.x) | ((unsigned int)f2bf(v.y) << 16);
    p.y = (unsigned int)f2bf(v.z) | ((unsigned int)f2bf(v.w) << 16);
    *(uint2*)(xb + i) = p;
}

// ---------------- WcatT (bf16, transposed [NCAT][256]) + bcat ----------------
__global__ __launch_bounds__(256) void wcat_kernel(
    const float* __restrict__ Wq, const float* __restrict__ Wk,
    const float* __restrict__ Wv, const float* __restrict__ Ws,
    const float* __restrict__ We,
    const float* __restrict__ bq, const float* __restrict__ bk,
    const float* __restrict__ bv, const float* __restrict__ bs,
    unsigned short* __restrict__ WcatT, float* __restrict__ bcat)
{
    int col = blockIdx.x;
    int kr  = threadIdx.x;
    float w;
    if (col < 512) {
        int s = col >> 7, c = col & 127;
        const float* W = (s == 0) ? Wq : (s == 1) ? Wk : (s == 2) ? Wv : Ws;
        w = W[kr * OUT_SIZE + c];
    } else {
        int d = col - 512;
        float a = 0.f;
        #pragma unroll 8
        for (int c = 0; c < OUT_SIZE; c++)
            a = fmaf(Wq[kr * OUT_SIZE + c], We[d * OUT_SIZE + c], a);
        w = a;
    }
    WcatT[(size_t)col * 256 + kr] = f2bf(w);
    if (kr == 0) {
        float b;
        if (col < 512) {
            int s = col >> 7, c = col & 127;
            b = ((s == 0) ? bq : (s == 1) ? bk : (s == 2) ? bv : bs)[c];
        } else {
            int d = col - 512;
            b = 0.f;
            for (int c = 0; c < OUT_SIZE; c++)
                b = fmaf(bq[c], We[d * OUT_SIZE + c], b);
        }
        bcat[col] = b;
    }
}

// ---------------- MFMA mega GEMM: [q|k|v|sk|q2] = xb @ WcatT^T + bcat ----------------
__global__ __launch_bounds__(256) void gemm_kernel(
    const unsigned short* __restrict__ xb,     // [N_NODES][256] bf16
    const unsigned short* __restrict__ WcatT,  // [NCAT][256] bf16
    const float* __restrict__ bcat,
    float* __restrict__ qbuf, unsigned short* __restrict__ kb16,
    unsigned short* __restrict__ vb16, float* __restrict__ skbuf,
    float* __restrict__ q2buf)
{
    __shared__ __align__(16) unsigned short Als[128 * 32];  // [row][32]
    __shared__ __align__(16) unsigned short Bls[64 * 32];   // [n][32]

    const int t    = threadIdx.x;
    const int wave = t >> 6;
    const int lane = t & 63;
    const int quad = lane >> 4;
    const int l16  = lane & 15;

    const int m0 = blockIdx.x * 128;
    const int n0 = blockIdx.y * 64;

    floatx4 acc[2][4];
    #pragma unroll
    for (int mt = 0; mt < 2; mt++)
        #pragma unroll
        for (int nt = 0; nt < 4; nt++)
            acc[mt][nt] = (floatx4){0.f, 0.f, 0.f, 0.f};

    for (int k0 = 0; k0 < IN_SIZE; k0 += 32) {
        if (k0) __syncthreads();
        #pragma unroll
        for (int r = 0; r < 2; r++) {
            int idx = r * 256 + t;
            int row = idx >> 2;
            int c8  = idx & 3;
            int grow = m0 + row;
            if (grow >= N_NODES) grow = N_NODES - 1;
            const unsigned short* g = xb + (size_t)grow * IN_SIZE + k0 + c8 * 8;
            __builtin_amdgcn_global_load_lds(GPTR(g), LPTR(Als + (size_t)(r * 256 + wave * 64) * 8), 16, 0, 0);
        }
        {
            int n  = t >> 2;
            int c8 = t & 3;
            const unsigned short* g = WcatT + (size_t)(n0 + n) * 256 + k0 + c8 * 8;
            __builtin_amdgcn_global_load_lds(GPTR(g), LPTR(Bls + (size_t)(wave * 64) * 8), 16, 0, 0);
        }
        __syncthreads();

        short8 af[2], bf[4];
        #pragma unroll
        for (int mt = 0; mt < 2; mt++)
            af[mt] = *(const short8*)(Als + (size_t)(wave * 32 + mt * 16 + l16) * 32 + quad * 8);
        #pragma unroll
        for (int nt = 0; nt < 4; nt++)
            bf[nt] = *(const short8*)(Bls + (size_t)(nt * 16 + l16) * 32 + quad * 8);
        #pragma unroll
        for (int mt = 0; mt < 2; mt++)
            #pragma unroll
            for (int nt = 0; nt < 4; nt++)
                acc[mt][nt] = __builtin_amdgcn_mfma_f32_16x16x32_bf16(af[mt], bf[nt], acc[mt][nt], 0, 0, 0);
    }

    const int seg = blockIdx.y;  // 0,1:q  2,3:k  4,5:v  6,7:sk  8:q2
    #pragma unroll
    for (int mt = 0; mt < 2; mt++) {
        #pragma unroll
        for (int r = 0; r < 4; r++) {
            int row = m0 + wave * 32 + mt * 16 + quad * 4 + r;
            if (row >= N_NODES) continue;
            #pragma unroll
            for (int nt = 0; nt < 4; nt++) {
                int c = n0 + nt * 16 + l16;
                float val = acc[mt][nt][r] + bcat[c];
                if (seg < 2)      qbuf[(size_t)row * OUT_SIZE + c] = val;
                else if (seg < 4) kb16[(size_t)row * OUT_SIZE + (c - 128)] = f2bf(val);
                else if (seg < 6) vb16[(size_t)row * OUT_SIZE + (c - 256)] = f2bf(val);
                else if (seg < 8) skbuf[(size_t)row * OUT_SIZE + (c - 384)] = val;
                else              q2buf[(size_t)row * EDGE_DIM + (c - 512)] = val;
            }
        }
    }
}

// ---------------- CSR build ----------------
__global__ __launch_bounds__(256) void hist_kernel(
    const int* __restrict__ ei, int* __restrict__ counts)
{
    int e = blockIdx.x * 256 + threadIdx.x;
    if (e >= N_EDGES) return;
    atomicAdd(&counts[ei[N_EDGES + e]], 1);
}

__global__ __launch_bounds__(SCAN_B) void scan1_kernel(
    const int* __restrict__ counts, int* __restrict__ incl, int* __restrict__ bsum)
{
    __shared__ int tmp[SCAN_B];
    int i = blockIdx.x * SCAN_B + threadIdx.x;
    int val = (i < N_NODES) ? counts[i] : 0;
    tmp[threadIdx.x] = val;
    __syncthreads();
    for (int off = 1; off < SCAN_B; off <<= 1) {
        int t = (threadIdx.x >= off) ? tmp[threadIdx.x - off] : 0;
        __syncthreads();
        tmp[threadIdx.x] += t;
        __syncthreads();
    }
    if (i < N_NODES) incl[i] = tmp[threadIdx.x];
    if (threadIdx.x == SCAN_B - 1) bsum[blockIdx.x] = tmp[SCAN_B - 1];
}

__global__ __launch_bounds__(SCAN_B) void scan2_kernel(int* __restrict__ bsum)
{
    __shared__ int tmp[SCAN_B];
    int val = (threadIdx.x < NBLK) ? bsum[threadIdx.x] : 0;
    tmp[threadIdx.x] = val;
    __syncthreads();
    for (int off = 1; off < SCAN_B; off <<= 1) {
        int t = (threadIdx.x >= off) ? tmp[threadIdx.x - off] : 0;
        __syncthreads();
        tmp[threadIdx.x] += t;
        __syncthreads();
    }
    if (threadIdx.x < NBLK) bsum[threadIdx.x] = tmp[threadIdx.x];
}

__global__ __launch_bounds__(SCAN_B) void scan3_kernel(
    const int* __restrict__ incl, const int* __restrict__ bsum,
    const int* __restrict__ counts, int* __restrict__ rowptr, int* __restrict__ cursor)
{
    int i = blockIdx.x * SCAN_B + threadIdx.x;
    if (i >= N_NODES) return;
    int off = (blockIdx.x == 0) ? 0 : bsum[blockIdx.x - 1];
    int inc = incl[i] + off;
    rowptr[i + 1] = inc;
    cursor[i] = inc - counts[i];
    if (i == 0) rowptr[0] = 0;
}

__global__ __launch_bounds__(256) void scatter_kernel(
    const int* __restrict__ ei, int* __restrict__ cursor,
    int2* __restrict__ csr_se)
{
    int e = blockIdx.x * 256 + threadIdx.x;
    if (e >= N_EDGES) return;
    int dst = ei[N_EDGES + e];
    int pos = atomicAdd(&cursor[dst], 1);
    csr_se[pos] = make_int2(ei[e], e);
}

// ---------------- fused per-dst-node ----------------
// One wave per node; wave split into 4 groups of 16 lanes. Each group owns an
// independent edge sub-stream (stride 4) with its own online-softmax state.
// Lane layout within a group: lane l16 owns channels c = l16*8..l16*8+7 and
// edge-dims d = l16*4..l16*4+3. Dot-reduce depth is 4 (xor 1/2/4/8); the 4
// group states merge once at the end (xor 16/32, -inf-guarded).
__global__ __launch_bounds__(256) void fused_kernel(
    const int* __restrict__ rowptr, const int2* __restrict__ csr_se,
    const float* __restrict__ qbuf, const unsigned short* __restrict__ kb16,
    const unsigned short* __restrict__ vb16, const float* __restrict__ q2buf,
    const float* __restrict__ ea, const float* __restrict__ skbuf,
    const float* __restrict__ We, const float* __restrict__ be,
    float* __restrict__ out)
{
    int node = blockIdx.x * 4 + (threadIdx.x >> 6);
    if (node >= N_NODES) return;
    const int lane = threadIdx.x & 63;
    const int g    = lane >> 4;
    const int l16  = lane & 15;
    const int beg = rowptr[node];
    const int end = rowptr[node + 1];

    const float4* qp = (const float4*)(qbuf + (size_t)node * OUT_SIZE);
    float4 qa = qp[2 * l16], qb = qp[2 * l16 + 1];
    float q8[8] = {qa.x, qa.y, qa.z, qa.w, qb.x, qb.y, qb.z, qb.w};
    float4 q2v = ((const float4*)(q2buf + (size_t)node * EDGE_DIM))[l16];
    const float4* bep = (const float4*)be;
    float4 ba = bep[2 * l16], bb = bep[2 * l16 + 1];
    float be8[8] = {ba.x, ba.y, ba.z, ba.w, bb.x, bb.y, bb.z, bb.w};

    // qbv = q . be (per node constant)
    float qbv = 0.f;
    #pragma unroll
    for (int j = 0; j < 8; j++) qbv = fmaf(q8[j], be8[j], qbv);
    #pragma unroll
    for (int off = 1; off < 16; off <<= 1) qbv += __shfl_xor(qbv, off);

    const float scale = 0.08838834764831845f;  // 1/sqrt(128)
    float m = -INFINITY, l = 0.f;
    float vacc[8] = {0.f, 0.f, 0.f, 0.f, 0.f, 0.f, 0.f, 0.f};
    float eacc[4] = {0.f, 0.f, 0.f, 0.f};

    int i = beg + g;
    for (; i + 4 < end; i += 8) {
        int2 se1 = csr_se[i];
        int2 se2 = csr_se[i + 4];
        uint4 k1 = ((const uint4*)(kb16 + (size_t)se1.x * OUT_SIZE))[l16];
        uint4 k2 = ((const uint4*)(kb16 + (size_t)se2.x * OUT_SIZE))[l16];
        uint4 v1 = ((const uint4*)(vb16 + (size_t)se1.x * OUT_SIZE))[l16];
        uint4 v2 = ((const uint4*)(vb16 + (size_t)se2.x * OUT_SIZE))[l16];
        float4 e1 = ((const float4*)(ea + (size_t)se1.y * EDGE_DIM))[l16];
        float4 e2 = ((const float4*)(ea + (size_t)se2.y * EDGE_DIM))[l16];
        float kf1[8], kf2[8], vf1[8], vf2[8];
        unp8(k1, kf1); unp8(k2, kf2); unp8(v1, vf1); unp8(v2, vf2);

        float p1 = 0.f, p2 = 0.f;
        #pragma unroll
        for (int j = 0; j < 8; j++) { p1 = fmaf(q8[j], kf1[j], p1); p2 = fmaf(q8[j], kf2[j], p2); }
        p1 = fmaf(q2v.x, e1.x, p1); p1 = fmaf(q2v.y, e1.y, p1);
        p1 = fmaf(q2v.z, e1.z, p1); p1 = fmaf(q2v.w, e1.w, p1);
        p2 = fmaf(q2v.x, e2.x, p2); p2 = fmaf(q2v.y, e2.y, p2);
        p2 = fmaf(q2v.z, e2.z, p2); p2 = fmaf(q2v.w, e2.w, p2);
        #pragma unroll
        for (int off = 1; off < 16; off <<= 1) { p1 += __shfl_xor(p1, off); p2 += __shfl_xor(p2, off); }

        float s1 = (p1 + qbv) * scale;
        float s2 = (p2 + qbv) * scale;
        float mn = fmaxf(m, fmaxf(s1, s2));
        float sc  = __expf(m - mn);     // m=-inf on first iter: exp(-inf)=0, no NaN (mn finite)
        float pe1 = __expf(s1 - mn);
        float pe2 = __expf(s2 - mn);
        l = fmaf(l, sc, pe1 + pe2);
        #pragma unroll
        for (int j = 0; j < 8; j++)
            vacc[j] = fmaf(vacc[j], sc, fmaf(pe1, vf1[j], pe2 * vf2[j]));
        eacc[0] = fmaf(eacc[0], sc, fmaf(pe1, e1.x, pe2 * e2.x));
        eacc[1] = fmaf(eacc[1], sc, fmaf(pe1, e1.y, pe2 * e2.y));
        eacc[2] = fmaf(eacc[2], sc, fmaf(pe1, e1.z, pe2 * e2.z));
        eacc[3] = fmaf(eacc[3], sc, fmaf(pe1, e1.w, pe2 * e2.w));
        m = mn;
    }
    if (i < end) {
        int2 se1 = csr_se[i];
        uint4 k1 = ((const uint4*)(kb16 + (size_t)se1.x * OUT_SIZE))[l16];
        uint4 v1 = ((const uint4*)(vb16 + (size_t)se1.x * OUT_SIZE))[l16];
        float4 e1 = ((const float4*)(ea + (size_t)se1.y * EDGE_DIM))[l16];
        float kf1[8], vf1[8];
        unp8(k1, kf1); unp8(v1, vf1);
        float p1 = 0.f;
        #pragma unroll
        for (int j = 0; j < 8; j++) p1 = fmaf(q8[j], kf1[j], p1);
        p1 = fmaf(q2v.x, e1.x, p1); p1 = fmaf(q2v.y, e1.y, p1);
        p1 = fmaf(q2v.z, e1.z, p1); p1 = fmaf(q2v.w, e1.w, p1);
        #pragma unroll
        for (int off = 1; off < 16; off <<= 1) p1 += __shfl_xor(p1, off);
        float s1 = (p1 + qbv) * scale;
        float mn = fmaxf(m, s1);
        float sc  = __expf(m - mn);
        float pe1 = __expf(s1 - mn);
        l = fmaf(l, sc, pe1);
        #pragma unroll
        for (int j = 0; j < 8; j++) vacc[j] = fmaf(vacc[j], sc, pe1 * vf1[j]);
        eacc[0] = fmaf(eacc[0], sc, pe1 * e1.x);
        eacc[1] = fmaf(eacc[1], sc, pe1 * e1.y);
        eacc[2] = fmaf(eacc[2], sc, pe1 * e1.z);
        eacc[3] = fmaf(eacc[3], sc, pe1 * e1.w);
        m = mn;
    }

    // merge the 4 group states (butterfly over xor 16, 32); -inf-guarded so
    // empty groups (degree < 4) contribute 0 without generating NaN.
    #pragma unroll
    for (int off = 16; off <= 32; off <<= 1) {
        float mo = __shfl_xor(m, off);
        float lo = __shfl_xor(l, off);
        float mn = fmaxf(m, mo);
        float sa = (m  > -INFINITY) ? __expf(m  - mn) : 0.f;
        float sb = (mo > -INFINITY) ? __expf(mo - mn) : 0.f;
        l = l * sa + lo * sb;
        #pragma unroll
        for (int j = 0; j < 8; j++) {
            float vo = __shfl_xor(vacc[j], off);
            vacc[j] = vacc[j] * sa + vo * sb;
        }
        #pragma unroll
        for (int j = 0; j < 4; j++) {
            float eo = __shfl_xor(eacc[j], off);
            eacc[j] = eacc[j] * sa + eo * sb;
        }
        m = mn;
    }

    float inv  = 1.f / (l + 1e-16f);
    float aggA = l * inv;

    const float4* skp = (const float4*)(skbuf + (size_t)node * OUT_SIZE);
    float4 s0 = skp[2 * l16], s1v = skp[2 * l16 + 1];
    float sk8[8] = {s0.x, s0.y, s0.z, s0.w, s1v.x, s1v.y, s1v.z, s1v.w};

    float o[8];
    #pragma unroll
    for (int j = 0; j < 8; j++) o[j] = fmaf(vacc[j], inv, fmaf(aggA, be8[j], sk8[j]));

    // (sum_e a_e * ea_e) @ We : group g handles We rows d in [g*16, g*16+16)
    float wacc[8] = {0.f, 0.f, 0.f, 0.f, 0.f, 0.f, 0.f, 0.f};
    #pragma unroll
    for (int j = 0; j < 4; j++) {
        float ej = eacc[j] * inv;
        #pragma unroll
        for (int t = 0; t < 4; t++) {
            float gsc = __shfl(ej, (g << 2) + t);         // lane (g*4+t) holds d = g*16+t*4+j
            const float4* wr = (const float4*)(We + (size_t)((g << 4) + (t << 2) + j) * OUT_SIZE);
            float4 w0 = wr[2 * l16], w1 = wr[2 * l16 + 1];
            wacc[0] = fmaf(gsc, w0.x, wacc[0]); wacc[1] = fmaf(gsc, w0.y, wacc[1]);
            wacc[2] = fmaf(gsc, w0.z, wacc[2]); wacc[3] = fmaf(gsc, w0.w, wacc[3]);
            wacc[4] = fmaf(gsc, w1.x, wacc[4]); wacc[5] = fmaf(gsc, w1.y, wacc[5]);
            wacc[6] = fmaf(gsc, w1.z, wacc[6]); wacc[7] = fmaf(gsc, w1.w, wacc[7]);
        }
    }
    #pragma unroll
    for (int off = 16; off <= 32; off <<= 1)
        #pragma unroll
        for (int j = 0; j < 8; j++) wacc[j] += __shfl_xor(wacc[j], off);

    #pragma unroll
    for (int j = 0; j < 8; j++) {
        float v = o[j] + wacc[j];
        o[j] = (v > 0.f) ? v : (__expf(v) - 1.f);
    }
    if (lane < 32) {
        float4 w = (lane < 16) ? make_float4(o[0], o[1], o[2], o[3])
                               : make_float4(o[4], o[5], o[6], o[7]);
        ((float4*)(out + (size_t)node * OUT_SIZE))[2 * l16 + (lane >> 4)] = w;
    }
}

extern "C" void kernel_launch(void* const* d_in, const int* in_sizes, int n_in,
                              void* d_out, int out_size, void* d_ws, size_t ws_size,
                              hipStream_t stream) {
    const float* x   = (const float*)d_in[0];
    const int*   ei  = (const int*)d_in[1];
    const float* ea  = (const float*)d_in[2];
    const float* Wq  = (const float*)d_in[3];
    const float* bq  = (const float*)d_in[4];
    const float* Wk  = (const float*)d_in[5];
    const float* bk  = (const float*)d_in[6];
    const float* Wv  = (const float*)d_in[7];
    const float* bv  = (const float*)d_in[8];
    const float* We  = (const float*)d_in[9];
    const float* be  = (const float*)d_in[10];
    const float* Ws  = (const float*)d_in[11];
    const float* bs  = (const float*)d_in[12];
    float* out = (float*)d_out;

    // workspace layout
    float* ws0   = (float*)d_ws;
    float* qbuf  = ws0;                                     // 6.4M f
    float* skbuf = qbuf  + (size_t)N_NODES * OUT_SIZE;      // 6.4M f
    float* q2buf = skbuf + (size_t)N_NODES * OUT_SIZE;      // 3.2M f
    unsigned short* kb16 = (unsigned short*)(q2buf + (size_t)N_NODES * EDGE_DIM); // 6.4M sh
    unsigned short* vb16 = kb16 + (size_t)N_NODES * OUT_SIZE;                     // 6.4M sh
    unsigned short* xb   = vb16 + (size_t)N_NODES * OUT_SIZE;                     // 12.8M sh
    unsigned short* WcatT = xb + (size_t)N_NODES * IN_SIZE;                       // 147456 sh
    float* bcat  = (float*)(WcatT + (size_t)NCAT * 256);    // 576 f
    int* counts  = (int*)(bcat + NCAT);                     // 50K
    int* incl    = counts + N_NODES;
    int* bsum    = incl + N_NODES;                          // 256
    int* rowptr  = bsum + 256;                              // 50K+1
    int* cursor  = rowptr + N_NODES + 1;                    // 50K
    int2* csr_se = (int2*)(cursor + N_NODES + 1);           // 800K int2 (8B aligned)

    hipMemsetAsync(counts, 0, (size_t)N_NODES * sizeof(int), stream);

    // CSR build
    hist_kernel<<<(N_EDGES + 255) / 256, 256, 0, stream>>>(ei, counts);
    scan1_kernel<<<NBLK, SCAN_B, 0, stream>>>(counts, incl, bsum);
    scan2_kernel<<<1, SCAN_B, 0, stream>>>(bsum);
    scan3_kernel<<<NBLK, SCAN_B, 0, stream>>>(incl, bsum, counts, rowptr, cursor);
    scatter_kernel<<<(N_EDGES + 255) / 256, 256, 0, stream>>>(ei, cursor, csr_se);

    // bf16 conversions / weights
    xcast_kernel<<<(N_NODES * IN_SIZE / 4 + 255) / 256, 256, 0, stream>>>(x, xb);
    wcat_kernel<<<NCAT, 256, 0, stream>>>(Wq, Wk, Wv, Ws, We, bq, bk, bv, bs, WcatT, bcat);

    // MFMA mega GEMM
    dim3 gG((N_NODES + 127) / 128, 9);
    gemm_kernel<<<gG, 256, 0, stream>>>(xb, WcatT, bcat, qbuf, kb16, vb16, skbuf, q2buf);

    // fused edge phase + epilogue
    fused_kernel<<<(N_NODES + 3) / 4, 256, 0, stream>>>(
        rowptr, csr_se, qbuf, kb16, vb16,
        q2buf, ea, skbuf, We, be, out);
}

// Round 3
// 589.136 us; speedup vs baseline: 1.0816x; 1.0243x over previous
//
#include <hip/hip_runtime.h>
#include <hip/hip_bf16.h>
#include <math.h>

#define N_NODES 50000
#define N_EDGES 800000
#define IN_SIZE 256
#define OUT_SIZE 128
#define EDGE_DIM 64
#define NCAT 576   // [q:0-127 | k:128-255 | v:256-383 | sk:384-511 | q2:512-575]

#define SCAN_B 256
#define NBLK ((N_NODES + SCAN_B - 1) / SCAN_B)   // 196

typedef __attribute__((ext_vector_type(8))) short short8;
typedef __attribute__((ext_vector_type(4))) float floatx4;

#define GPTR(p) ((const __attribute__((address_space(1))) void*)(p))
#define LPTR(p) ((__attribute__((address_space(3))) void*)(p))

__device__ __forceinline__ unsigned short f2bf(float f) {
    unsigned int u = __float_as_uint(f);
    unsigned int r = (u + 0x7fffu + ((u >> 16) & 1u)) >> 16;  // RNE
    return (unsigned short)r;
}
__device__ __forceinline__ float2 bf2_to_f2(unsigned int u) {
    float2 r;
    r.x = __uint_as_float(u << 16);
    r.y = __uint_as_float(u & 0xffff0000u);
    return r;
}
__device__ __forceinline__ void unp8(uint4 u, float* f) {
    float2 t;
    t = bf2_to_f2(u.x); f[0] = t.x; f[1] = t.y;
    t = bf2_to_f2(u.y); f[2] = t.x; f[3] = t.y;
    t = bf2_to_f2(u.z); f[4] = t.x; f[5] = t.y;
    t = bf2_to_f2(u.w); f[6] = t.x; f[7] = t.y;
}

// ---------------- x -> bf16 ----------------
__global__ __launch_bounds__(256) void xcast_kernel(
    const float* __restrict__ x, unsigned short* __restrict__ xb)
{
    size_t i = ((size_t)blockIdx.x * 256 + threadIdx.x) * 4;
    float4 v = *(const float4*)(x + i);
    uint2 p;
    p.x = (unsigned int)f2bf(v.x) | ((unsigned int)f2bf(v.y) << 16);
    p.y = (unsigned int)f2bf(v.z) | ((unsigned int)f2bf(v.w) << 16);
    *(uint2*)(xb + i) = p;
}

// ---------------- WcatT (bf16, transposed [NCAT][256]) + bcat ----------------
__global__ __launch_bounds__(256) void wcat_kernel(
    const float* __restrict__ Wq, const float* __restrict__ Wk,
    const float* __restrict__ Wv, const float* __restrict__ Ws,
    const float* __restrict__ We,
    const float* __restrict__ bq, const float* __restrict__ bk,
    const float* __restrict__ bv, const float* __restrict__ bs,
    unsigned short* __restrict__ WcatT, float* __restrict__ bcat)
{
    int col = blockIdx.x;
    int kr  = threadIdx.x;
    float w;
    if (col < 512) {
        int s = col >> 7, c = col & 127;
        const float* W = (s == 0) ? Wq : (s == 1) ? Wk : (s == 2) ? Wv : Ws;
        w = W[kr * OUT_SIZE + c];
    } else {
        int d = col - 512;
        float a = 0.f;
        #pragma unroll 8
        for (int c = 0; c < OUT_SIZE; c++)
            a = fmaf(Wq[kr * OUT_SIZE + c], We[d * OUT_SIZE + c], a);
        w = a;
    }
    WcatT[(size_t)col * 256 + kr] = f2bf(w);
    if (kr == 0) {
        float b;
        if (col < 512) {
            int s = col >> 7, c = col & 127;
            b = ((s == 0) ? bq : (s == 1) ? bk : (s == 2) ? bv : bs)[c];
        } else {
            int d = col - 512;
            b = 0.f;
            for (int c = 0; c < OUT_SIZE; c++)
                b = fmaf(bq[c], We[d * OUT_SIZE + c], b);
        }
        bcat[col] = b;
    }
}

// ---------------- MFMA mega GEMM: [q|k|v|sk|q2] = xb @ WcatT^T + bcat ----------------
__global__ __launch_bounds__(256) void gemm_kernel(
    const unsigned short* __restrict__ xb,     // [N_NODES][256] bf16
    const unsigned short* __restrict__ WcatT,  // [NCAT][256] bf16
    const float* __restrict__ bcat,
    float* __restrict__ qbuf, unsigned short* __restrict__ kvb,
    float* __restrict__ skbuf, float* __restrict__ q2buf)
{
    __shared__ __align__(16) unsigned short Als[128 * 32];  // [row][32]
    __shared__ __align__(16) unsigned short Bls[64 * 32];   // [n][32]

    const int t    = threadIdx.x;
    const int wave = t >> 6;
    const int lane = t & 63;
    const int quad = lane >> 4;
    const int l16  = lane & 15;

    const int m0 = blockIdx.x * 128;
    const int n0 = blockIdx.y * 64;

    floatx4 acc[2][4];
    #pragma unroll
    for (int mt = 0; mt < 2; mt++)
        #pragma unroll
        for (int nt = 0; nt < 4; nt++)
            acc[mt][nt] = (floatx4){0.f, 0.f, 0.f, 0.f};

    for (int k0 = 0; k0 < IN_SIZE; k0 += 32) {
        if (k0) __syncthreads();
        #pragma unroll
        for (int r = 0; r < 2; r++) {
            int idx = r * 256 + t;
            int row = idx >> 2;
            int c8  = idx & 3;
            int grow = m0 + row;
            if (grow >= N_NODES) grow = N_NODES - 1;
            const unsigned short* g = xb + (size_t)grow * IN_SIZE + k0 + c8 * 8;
            __builtin_amdgcn_global_load_lds(GPTR(g), LPTR(Als + (size_t)(r * 256 + wave * 64) * 8), 16, 0, 0);
        }
        {
            int n  = t >> 2;
            int c8 = t & 3;
            const unsigned short* g = WcatT + (size_t)(n0 + n) * 256 + k0 + c8 * 8;
            __builtin_amdgcn_global_load_lds(GPTR(g), LPTR(Bls + (size_t)(wave * 64) * 8), 16, 0, 0);
        }
        __syncthreads();

        short8 af[2], bf[4];
        #pragma unroll
        for (int mt = 0; mt < 2; mt++)
            af[mt] = *(const short8*)(Als + (size_t)(wave * 32 + mt * 16 + l16) * 32 + quad * 8);
        #pragma unroll
        for (int nt = 0; nt < 4; nt++)
            bf[nt] = *(const short8*)(Bls + (size_t)(nt * 16 + l16) * 32 + quad * 8);
        #pragma unroll
        for (int mt = 0; mt < 2; mt++)
            #pragma unroll
            for (int nt = 0; nt < 4; nt++)
                acc[mt][nt] = __builtin_amdgcn_mfma_f32_16x16x32_bf16(af[mt], bf[nt], acc[mt][nt], 0, 0, 0);
    }

    const int seg = blockIdx.y;  // 0,1:q  2,3:k  4,5:v  6,7:sk  8:q2
    #pragma unroll
    for (int mt = 0; mt < 2; mt++) {
        #pragma unroll
        for (int r = 0; r < 4; r++) {
            int row = m0 + wave * 32 + mt * 16 + quad * 4 + r;
            if (row >= N_NODES) continue;
            #pragma unroll
            for (int nt = 0; nt < 4; nt++) {
                int c = n0 + nt * 16 + l16;
                float val = acc[mt][nt][r] + bcat[c];
                if (seg < 2)      qbuf[(size_t)row * OUT_SIZE + c] = val;
                else if (seg < 4) kvb[(size_t)row * 256 + (c - 128)] = f2bf(val);       // k at 0..127
                else if (seg < 6) kvb[(size_t)row * 256 + 128 + (c - 256)] = f2bf(val); // v at 128..255
                else if (seg < 8) skbuf[(size_t)row * OUT_SIZE + (c - 384)] = val;
                else              q2buf[(size_t)row * EDGE_DIM + (c - 512)] = val;
            }
        }
    }
}

// ---------------- CSR build ----------------
__global__ __launch_bounds__(256) void hist_kernel(
    const int* __restrict__ ei, int* __restrict__ counts)
{
    int e = blockIdx.x * 256 + threadIdx.x;
    if (e >= N_EDGES) return;
    atomicAdd(&counts[ei[N_EDGES + e]], 1);
}

__global__ __launch_bounds__(SCAN_B) void scan1_kernel(
    const int* __restrict__ counts, int* __restrict__ incl, int* __restrict__ bsum)
{
    __shared__ int tmp[SCAN_B];
    int i = blockIdx.x * SCAN_B + threadIdx.x;
    int val = (i < N_NODES) ? counts[i] : 0;
    tmp[threadIdx.x] = val;
    __syncthreads();
    for (int off = 1; off < SCAN_B; off <<= 1) {
        int t = (threadIdx.x >= off) ? tmp[threadIdx.x - off] : 0;
        __syncthreads();
        tmp[threadIdx.x] += t;
        __syncthreads();
    }
    if (i < N_NODES) incl[i] = tmp[threadIdx.x];
    if (threadIdx.x == SCAN_B - 1) bsum[blockIdx.x] = tmp[SCAN_B - 1];
}

__global__ __launch_bounds__(SCAN_B) void scan2_kernel(int* __restrict__ bsum)
{
    __shared__ int tmp[SCAN_B];
    int val = (threadIdx.x < NBLK) ? bsum[threadIdx.x] : 0;
    tmp[threadIdx.x] = val;
    __syncthreads();
    for (int off = 1; off < SCAN_B; off <<= 1) {
        int t = (threadIdx.x >= off) ? tmp[threadIdx.x - off] : 0;
        __syncthreads();
        tmp[threadIdx.x] += t;
        __syncthreads();
    }
    if (threadIdx.x < NBLK) bsum[threadIdx.x] = tmp[threadIdx.x];
}

__global__ __launch_bounds__(SCAN_B) void scan3_kernel(
    const int* __restrict__ incl, const int* __restrict__ bsum,
    const int* __restrict__ counts, int* __restrict__ rowptr, int* __restrict__ cursor)
{
    int i = blockIdx.x * SCAN_B + threadIdx.x;
    if (i >= N_NODES) return;
    int off = (blockIdx.x == 0) ? 0 : bsum[blockIdx.x - 1];
    int inc = incl[i] + off;
    rowptr[i + 1] = inc;
    cursor[i] = inc - counts[i];
    if (i == 0) rowptr[0] = 0;
}

__global__ __launch_bounds__(256) void scatter_kernel(
    const int* __restrict__ ei, int* __restrict__ cursor,
    int2* __restrict__ csr_se)
{
    int e = blockIdx.x * 256 + threadIdx.x;
    if (e >= N_EDGES) return;
    int dst = ei[N_EDGES + e];
    int pos = atomicAdd(&cursor[dst], 1);
    csr_se[pos] = make_int2(ei[e], e);
}

// ---------------- fused per-dst-node ----------------
// 4 waves/block, 4 independent 16-lane groups per wave, ONE NODE PER GROUP
// (16 nodes per block). No cross-group communication. Lane l16 owns channels
// c = l16*8..+7 and edge-dims d = l16*4..+3. 2 edges per group per iteration,
// with csr_se prefetched 2 pairs ahead and k/v/ea gathers issued 1 pair ahead
// (2-deep software pipeline). k and v interleaved in kvb[node][256].
__global__ __launch_bounds__(256) void fused_kernel(
    const int* __restrict__ rowptr, const int2* __restrict__ csr_se,
    const float* __restrict__ qbuf, const unsigned short* __restrict__ kvb,
    const float* __restrict__ q2buf,
    const float* __restrict__ ea, const float* __restrict__ skbuf,
    const float* __restrict__ We, const float* __restrict__ be,
    float* __restrict__ out)
{
    const int tid  = threadIdx.x;
    const int wave = tid >> 6;
    const int lane = tid & 63;
    const int g    = lane >> 4;
    const int l16  = lane & 15;

    int node = blockIdx.x * 16 + wave * 4 + g;
    const int vnode = (node < N_NODES) ? node : (N_NODES - 1);

    int beg = rowptr[vnode];
    int end = rowptr[vnode + 1];
    if (node >= N_NODES) { beg = 0; end = 0; }

    const float4* qp = (const float4*)(qbuf + (size_t)vnode * OUT_SIZE);
    float4 qa = qp[2 * l16], qb = qp[2 * l16 + 1];
    float4 q2v = ((const float4*)(q2buf + (size_t)vnode * EDGE_DIM))[l16];
    const float4* bep = (const float4*)be;
    float4 ba = bep[2 * l16], bb = bep[2 * l16 + 1];
    float q8[8] = {qa.x, qa.y, qa.z, qa.w, qb.x, qb.y, qb.z, qb.w};

    // qbv = q . be (per-node constant), 16-lane reduce
    float qbv = qa.x * ba.x + qa.y * ba.y + qa.z * ba.z + qa.w * ba.w
              + qb.x * bb.x + qb.y * bb.y + qb.z * bb.z + qb.w * bb.w;
    #pragma unroll
    for (int off = 1; off < 16; off <<= 1) qbv += __shfl_xor(qbv, off);

    const float scale = 0.08838834764831845f;  // 1/sqrt(128)
    float m = -INFINITY, l = 0.f;
    float vacc[8] = {0.f, 0.f, 0.f, 0.f, 0.f, 0.f, 0.f, 0.f};
    float eacc[4] = {0.f, 0.f, 0.f, 0.f};

    // ---- software-pipelined edge loop: 2 edges/iter ----
    int i = beg;
    uint4 kr1 = {}, kr2 = {}, vr1 = {}, vr2 = {};
    float4 er1 = {}, er2 = {};
    int2 nA = make_int2(0, 0), nB = make_int2(0, 0);
    bool curB = false;
    if (i < end) {
        int2 cA = csr_se[i];
        curB = (i + 1 < end);
        int2 cB = curB ? csr_se[i + 1] : cA;
        kr1 = ((const uint4*)(kvb + (size_t)cA.x * 256))[l16];
        vr1 = ((const uint4*)(kvb + (size_t)cA.x * 256 + 128))[l16];
        kr2 = ((const uint4*)(kvb + (size_t)cB.x * 256))[l16];
        vr2 = ((const uint4*)(kvb + (size_t)cB.x * 256 + 128))[l16];
        er1 = ((const float4*)(ea + (size_t)cA.y * EDGE_DIM))[l16];
        er2 = ((const float4*)(ea + (size_t)cB.y * EDGE_DIM))[l16];
        if (i + 2 < end) nA = csr_se[i + 2];
        if (i + 3 < end) nB = csr_se[i + 3];
    }
    while (i < end) {
        bool hasN = (i + 2 < end);
        bool nxtB = (i + 3 < end);
        // issue next pair's gathers (dummy row 0 if none: valid memory, unused)
        int2 xA = hasN ? nA : make_int2(0, 0);
        int2 xB = nxtB ? nB : xA;
        uint4 nk1 = ((const uint4*)(kvb + (size_t)xA.x * 256))[l16];
        uint4 nv1 = ((const uint4*)(kvb + (size_t)xA.x * 256 + 128))[l16];
        uint4 nk2 = ((const uint4*)(kvb + (size_t)xB.x * 256))[l16];
        uint4 nv2 = ((const uint4*)(kvb + (size_t)xB.x * 256 + 128))[l16];
        float4 ne1 = ((const float4*)(ea + (size_t)xA.y * EDGE_DIM))[l16];
        float4 ne2 = ((const float4*)(ea + (size_t)xB.y * EDGE_DIM))[l16];
        // prefetch se two pairs ahead
        if (i + 4 < end) nA = csr_se[i + 4];
        if (i + 5 < end) nB = csr_se[i + 5];

        // compute current pair
        float kf1[8], kf2[8], vf1[8], vf2[8];
        unp8(kr1, kf1); unp8(kr2, kf2); unp8(vr1, vf1); unp8(vr2, vf2);
        float p1 = 0.f, p2 = 0.f;
        #pragma unroll
        for (int j = 0; j < 8; j++) { p1 = fmaf(q8[j], kf1[j], p1); p2 = fmaf(q8[j], kf2[j], p2); }
        p1 = fmaf(q2v.x, er1.x, p1); p1 = fmaf(q2v.y, er1.y, p1);
        p1 = fmaf(q2v.z, er1.z, p1); p1 = fmaf(q2v.w, er1.w, p1);
        p2 = fmaf(q2v.x, er2.x, p2); p2 = fmaf(q2v.y, er2.y, p2);
        p2 = fmaf(q2v.z, er2.z, p2); p2 = fmaf(q2v.w, er2.w, p2);
        #pragma unroll
        for (int off = 1; off < 16; off <<= 1) { p1 += __shfl_xor(p1, off); p2 += __shfl_xor(p2, off); }

        float s1 = (p1 + qbv) * scale;
        float s2 = (p2 + qbv) * scale;
        float mn = fmaxf(m, fmaxf(s1, s2));
        float sc  = __expf(m - mn);     // m=-inf first iter: exp(-inf)=0 (mn finite)
        float pe1 = __expf(s1 - mn);
        float pe2 = __expf(s2 - mn);
        if (!curB) pe2 = 0.f;           // duplicated edge contributes nothing
        l = fmaf(l, sc, pe1 + pe2);
        #pragma unroll
        for (int j = 0; j < 8; j++)
            vacc[j] = fmaf(vacc[j], sc, fmaf(pe1, vf1[j], pe2 * vf2[j]));
        eacc[0] = fmaf(eacc[0], sc, fmaf(pe1, er1.x, pe2 * er2.x));
        eacc[1] = fmaf(eacc[1], sc, fmaf(pe1, er1.y, pe2 * er2.y));
        eacc[2] = fmaf(eacc[2], sc, fmaf(pe1, er1.z, pe2 * er2.z));
        eacc[3] = fmaf(eacc[3], sc, fmaf(pe1, er1.w, pe2 * er2.w));
        m = mn;

        // rotate pipeline
        kr1 = nk1; vr1 = nv1; kr2 = nk2; vr2 = nv2; er1 = ne1; er2 = ne2;
        curB = nxtB;
        i += 2;
    }

    float inv  = 1.f / (l + 1e-16f);
    float aggA = l * inv;

    const float4* skp = (const float4*)(skbuf + (size_t)vnode * OUT_SIZE);
    float4 s0 = skp[2 * l16], s1v = skp[2 * l16 + 1];

    float o[8];
    o[0] = fmaf(vacc[0], inv, fmaf(aggA, ba.x, s0.x));
    o[1] = fmaf(vacc[1], inv, fmaf(aggA, ba.y, s0.y));
    o[2] = fmaf(vacc[2], inv, fmaf(aggA, ba.z, s0.z));
    o[3] = fmaf(vacc[3], inv, fmaf(aggA, ba.w, s0.w));
    o[4] = fmaf(vacc[4], inv, fmaf(aggA, bb.x, s1v.x));
    o[5] = fmaf(vacc[5], inv, fmaf(aggA, bb.y, s1v.y));
    o[6] = fmaf(vacc[6], inv, fmaf(aggA, bb.z, s1v.z));
    o[7] = fmaf(vacc[7], inv, fmaf(aggA, bb.w, s1v.w));

    // (sum_e a_e * ea_e) @ We — full 64 rows per group; dim d = t*4+j lives in
    // lane (g*16+t) slot eacc[j]. We rows are identical across groups (L1 hit).
    float wacc[8] = {0.f, 0.f, 0.f, 0.f, 0.f, 0.f, 0.f, 0.f};
    #pragma unroll
    for (int j = 0; j < 4; j++) {
        float ej = eacc[j] * inv;
        #pragma unroll
        for (int t = 0; t < 16; t++) {
            float gsc = __shfl(ej, (g << 4) + t);
            const float4* wr = (const float4*)(We + (size_t)(t * 4 + j) * OUT_SIZE);
            float4 w0 = wr[2 * l16], w1 = wr[2 * l16 + 1];
            wacc[0] = fmaf(gsc, w0.x, wacc[0]); wacc[1] = fmaf(gsc, w0.y, wacc[1]);
            wacc[2] = fmaf(gsc, w0.z, wacc[2]); wacc[3] = fmaf(gsc, w0.w, wacc[3]);
            wacc[4] = fmaf(gsc, w1.x, wacc[4]); wacc[5] = fmaf(gsc, w1.y, wacc[5]);
            wacc[6] = fmaf(gsc, w1.z, wacc[6]); wacc[7] = fmaf(gsc, w1.w, wacc[7]);
        }
    }

    #pragma unroll
    for (int j = 0; j < 8; j++) {
        float v = o[j] + wacc[j];
        o[j] = (v > 0.f) ? v : (__expf(v) - 1.f);
    }
    if (node < N_NODES) {
        float4* op = (float4*)(out + (size_t)node * OUT_SIZE);
        op[2 * l16]     = make_float4(o[0], o[1], o[2], o[3]);
        op[2 * l16 + 1] = make_float4(o[4], o[5], o[6], o[7]);
    }
}

extern "C" void kernel_launch(void* const* d_in, const int* in_sizes, int n_in,
                              void* d_out, int out_size, void* d_ws, size_t ws_size,
                              hipStream_t stream) {
    const float* x   = (const float*)d_in[0];
    const int*   ei  = (const int*)d_in[1];
    const float* ea  = (const float*)d_in[2];
    const float* Wq  = (const float*)d_in[3];
    const float* bq  = (const float*)d_in[4];
    const float* Wk  = (const float*)d_in[5];
    const float* bk  = (const float*)d_in[6];
    const float* Wv  = (const float*)d_in[7];
    const float* bv  = (const float*)d_in[8];
    const float* We  = (const float*)d_in[9];
    const float* be  = (const float*)d_in[10];
    const float* Ws  = (const float*)d_in[11];
    const float* bs  = (const float*)d_in[12];
    float* out = (float*)d_out;

    // workspace layout
    float* ws0   = (float*)d_ws;
    float* qbuf  = ws0;                                     // 6.4M f
    float* skbuf = qbuf  + (size_t)N_NODES * OUT_SIZE;      // 6.4M f
    float* q2buf = skbuf + (size_t)N_NODES * OUT_SIZE;      // 3.2M f
    unsigned short* kvb = (unsigned short*)(q2buf + (size_t)N_NODES * EDGE_DIM); // 12.8M sh [k|v]
    unsigned short* xb   = kvb + (size_t)N_NODES * 256;                           // 12.8M sh
    unsigned short* WcatT = xb + (size_t)N_NODES * IN_SIZE;                       // 147456 sh
    float* bcat  = (float*)(WcatT + (size_t)NCAT * 256);    // 576 f
    int* counts  = (int*)(bcat + NCAT);                     // 50K
    int* incl    = counts + N_NODES;
    int* bsum    = incl + N_NODES;                          // 256
    int* rowptr  = bsum + 256;                              // 50K+1
    int* cursor  = rowptr + N_NODES + 1;                    // 50K
    int2* csr_se = (int2*)(cursor + N_NODES + 1);           // 800K int2 (8B aligned)

    hipMemsetAsync(counts, 0, (size_t)N_NODES * sizeof(int), stream);

    // CSR build
    hist_kernel<<<(N_EDGES + 255) / 256, 256, 0, stream>>>(ei, counts);
    scan1_kernel<<<NBLK, SCAN_B, 0, stream>>>(counts, incl, bsum);
    scan2_kernel<<<1, SCAN_B, 0, stream>>>(bsum);
    scan3_kernel<<<NBLK, SCAN_B, 0, stream>>>(incl, bsum, counts, rowptr, cursor);
    scatter_kernel<<<(N_EDGES + 255) / 256, 256, 0, stream>>>(ei, cursor, csr_se);

    // bf16 conversions / weights
    xcast_kernel<<<(N_NODES * IN_SIZE / 4 + 255) / 256, 256, 0, stream>>>(x, xb);
    wcat_kernel<<<NCAT, 256, 0, stream>>>(Wq, Wk, Wv, Ws, We, bq, bk, bv, bs, WcatT, bcat);

    // MFMA mega GEMM
    dim3 gG((N_NODES + 127) / 128, 9);
    gemm_kernel<<<gG, 256, 0, stream>>>(xb, WcatT, bcat, qbuf, kvb, skbuf, q2buf);

    // fused edge phase + epilogue
    fused_kernel<<<(N_NODES + 15) / 16, 256, 0, stream>>>(
        rowptr, csr_se, qbuf, kvb, q2buf, ea, skbuf, We, be, out);
}